// Round 1
// baseline (392.624 us; speedup 1.0000x reference)
//
#include <hip/hip_runtime.h>
#include <math.h>

#define BB 4
#define LL 256
#define HH 256
#define DH 64
#define MM (BB*LL)          // 1024 rows
#define NEGV -4294967295.0f

// ---------------- RMSNorm: one row (256 floats) per block ----------------
__global__ __launch_bounds__(256) void rmsnorm_kernel(
    const float* __restrict__ x, const float* __restrict__ w, float* __restrict__ y)
{
    int row = blockIdx.x;
    int tid = threadIdx.x;
    float v = x[(size_t)row * HH + tid];
    float ss = v * v;
    #pragma unroll
    for (int m = 1; m < 64; m <<= 1) ss += __shfl_xor(ss, m);
    __shared__ float red[4];
    if ((tid & 63) == 0) red[tid >> 6] = ss;
    __syncthreads();
    float tot = red[0] + red[1] + red[2] + red[3];
    float r = rsqrtf(tot * (1.0f / HH) + 1e-8f);
    y[(size_t)row * HH + tid] = v * r * w[tid];
}

// ---------------- GEMM: C[m,n] = sum_k A[m,k]*W[n,k] + bias[n] (+epilogue) --
// M=1024, N=256, K=256. grid (32,4): 32 row-blocks (BM=32), 4 col-blocks (BN=64).
__global__ __launch_bounds__(256) void gemm_kernel(
    const float* __restrict__ A, const float* __restrict__ W,
    const float* __restrict__ bias, const float* __restrict__ addv,
    const unsigned char* __restrict__ tl, float* __restrict__ C, int relu)
{
    __shared__ float4 A_s[32 * 64];           // 32 rows x 256 cols (as float4)
    int tid = threadIdx.x;
    int m0 = blockIdx.x * 32;
    int n0 = blockIdx.y * 64;
    const float4* A4 = (const float4*)(A + (size_t)m0 * HH);
    #pragma unroll
    for (int i = 0; i < 8; ++i) A_s[tid + i * 256] = A4[tid + i * 256];
    __syncthreads();

    int nl = tid & 63, ty = tid >> 6;         // wave = ty (all lanes same ty)
    int n = n0 + nl;
    const float4* W4 = (const float4*)(W + (size_t)n * HH);
    float acc[8];
    #pragma unroll
    for (int m = 0; m < 8; ++m) acc[m] = 0.f;

    #pragma unroll 4
    for (int k4 = 0; k4 < 64; ++k4) {
        float4 wv = W4[k4];
        #pragma unroll
        for (int m = 0; m < 8; ++m) {
            float4 av = A_s[(ty * 8 + m) * 64 + k4];  // wave-uniform -> LDS broadcast
            acc[m] = fmaf(av.x, wv.x, acc[m]);
            acc[m] = fmaf(av.y, wv.y, acc[m]);
            acc[m] = fmaf(av.z, wv.z, acc[m]);
            acc[m] = fmaf(av.w, wv.w, acc[m]);
        }
    }
    float bn = bias[n];
    #pragma unroll
    for (int m = 0; m < 8; ++m) {
        int row = m0 + ty * 8 + m;
        float v = acc[m] + bn;
        if (relu) v = fmaxf(v, 0.f);
        if (addv) v += addv[(size_t)row * HH + n];
        if (tl)   v *= (tl[row] ? 0.f : 1.f);
        C[(size_t)row * HH + n] = v;
    }
}

// ---------------- Attention: one workgroup per (b,q), all 4 heads ----------
// scores[h][k] = sum_d Q[h,q,d]*(Kp[k,hd]+tmK[q,k,hd]) ; masked softmax ;
// out[h,d]   = sum_k A[h][k]*(Vp[k,hd]+tmV[q,k,hd]) ; seqs += out
__global__ __launch_bounds__(256) void attn_kernel(
    const float* __restrict__ Q, const float* __restrict__ Kp,
    const float* __restrict__ Vp, const float* __restrict__ tmK,
    const float* __restrict__ tmV, const unsigned char* __restrict__ tl,
    float* __restrict__ s)
{
    int bq = blockIdx.x;
    int b = bq >> 8, q = bq & 255;
    int tid = threadIdx.x;
    int w = tid >> 6, lane = tid & 63;

    __shared__ float q_s[256];
    __shared__ float w_s[4][257];   // +1 pad: conflict-free column reads
    __shared__ float out_s[4][256];

    q_s[tid] = Q[(size_t)bq * HH + tid];
    __syncthreads();
    float4 qf = *(const float4*)&q_s[lane * 4];   // cols 4l..4l+3, head = lane>>4

    bool tlq = tl[bq] != 0;
    int kmax = tlq ? (LL - 1) : q;    // causal skip (exact: masked cols -> A==0)

    const float4* Kp4  = (const float4*)(Kp + (size_t)b * LL * HH);
    const float4* tmK4 = (const float4*)(tmK + (size_t)bq * LL * HH);

    // phase 1: scores. wave w handles k = w, w+4, ... (load balance over causal range)
    for (int k = w; k <= kmax; k += 4) {
        float4 kv = Kp4[k * 64 + lane];
        float4 tv = tmK4[k * 64 + lane];
        float sc = qf.x * (kv.x + tv.x) + qf.y * (kv.y + tv.y)
                 + qf.z * (kv.z + tv.z) + qf.w * (kv.w + tv.w);
        sc += __shfl_xor(sc, 1);
        sc += __shfl_xor(sc, 2);
        sc += __shfl_xor(sc, 4);
        sc += __shfl_xor(sc, 8);
        if ((lane & 15) == 0) w_s[lane >> 4][k] = sc;
    }
    __syncthreads();

    // mask + scale (masked entries never read their input value)
    for (int i = tid; i < 4 * 256; i += 256) {
        int h = i >> 8, k = i & 255;
        bool msk = tlq || (k > q);
        float v = w_s[h][k];
        w_s[h][k] = msk ? NEGV : v * 0.125f;   // 1/sqrt(64)
    }
    __syncthreads();

    // softmax over k: wave w handles head w
    {
        int h = w;
        float v0 = w_s[h][lane], v1 = w_s[h][lane + 64];
        float v2 = w_s[h][lane + 128], v3 = w_s[h][lane + 192];
        float mx = fmaxf(fmaxf(v0, v1), fmaxf(v2, v3));
        #pragma unroll
        for (int m2 = 1; m2 < 64; m2 <<= 1) mx = fmaxf(mx, __shfl_xor(mx, m2));
        float e0 = __expf(v0 - mx), e1 = __expf(v1 - mx);
        float e2 = __expf(v2 - mx), e3 = __expf(v3 - mx);
        float sm = e0 + e1 + e2 + e3;
        #pragma unroll
        for (int m2 = 1; m2 < 64; m2 <<= 1) sm += __shfl_xor(sm, m2);
        float inv = 1.0f / sm;
        w_s[h][lane] = e0 * inv;       w_s[h][lane + 64] = e1 * inv;
        w_s[h][lane + 128] = e2 * inv; w_s[h][lane + 192] = e3 * inv;
    }
    __syncthreads();

    // phase 2: out = A*(Vp+tmV)
    const float4* Vp4  = (const float4*)(Vp + (size_t)b * LL * HH);
    const float4* tmV4 = (const float4*)(tmV + (size_t)bq * LL * HH);
    float4 acc = {0.f, 0.f, 0.f, 0.f};
    int hh = lane >> 4;
    for (int k = w; k <= kmax; k += 4) {
        float a = w_s[hh][k];
        float4 vv = Vp4[k * 64 + lane];
        float4 tv = tmV4[k * 64 + lane];
        acc.x = fmaf(a, vv.x + tv.x, acc.x);
        acc.y = fmaf(a, vv.y + tv.y, acc.y);
        acc.z = fmaf(a, vv.z + tv.z, acc.z);
        acc.w = fmaf(a, vv.w + tv.w, acc.w);
    }
    *(float4*)&out_s[w][lane * 4] = acc;
    __syncthreads();

    float p = out_s[0][tid] + out_s[1][tid] + out_s[2][tid] + out_s[3][tid];
    s[(size_t)bq * HH + tid] += p;
}

extern "C" void kernel_launch(void* const* d_in, const int* in_sizes, int n_in,
                              void* d_out, int out_size, void* d_ws, size_t ws_size,
                              hipStream_t stream)
{
    const float* seqs = (const float*)d_in[0];
    // d_in[1] (attention_mask) is causal triu(k=1): computed analytically in-kernel.
    const unsigned char* tl = (const unsigned char*)d_in[2];  // all-zero timeline mask
    const float* tmK = (const float*)d_in[3];
    const float* tmV = (const float*)d_in[4];
    const float* apK = (const float*)d_in[5];
    const float* apV = (const float*)d_in[6];
    const float* ln_attn = (const float*)d_in[7];
    const float* Qw = (const float*)d_in[8];
    const float* Qb = (const float*)d_in[9];
    const float* Kw = (const float*)d_in[10];
    const float* Kb = (const float*)d_in[11];
    const float* Vw = (const float*)d_in[12];
    const float* Vb = (const float*)d_in[13];
    const float* ln_ffn = (const float*)d_in[14];
    const float* W1 = (const float*)d_in[15];
    const float* b1 = (const float*)d_in[16];
    const float* W2 = (const float*)d_in[17];
    const float* b2 = (const float*)d_in[18];
    const float* ln_last = (const float*)d_in[19];
    float* out = (float*)d_out;

    const size_t NROW = (size_t)MM * HH;   // 262144 floats
    float* s  = (float*)d_ws;
    float* xn = s  + NROW;
    float* qb = xn + NROW;
    float* kb = qb + NROW;
    float* vb = kb + NROW;
    float* tb = vb + NROW;

    hipMemcpyAsync(s, seqs, NROW * sizeof(float), hipMemcpyDeviceToDevice, stream);

    dim3 gg(32, 4), gbk(256);
    for (int i = 0; i < 2; ++i) {
        const float* Qwi = Qw + (size_t)i * HH * HH;
        const float* Kwi = Kw + (size_t)i * HH * HH;
        const float* Vwi = Vw + (size_t)i * HH * HH;
        const float* W1i = W1 + (size_t)i * HH * HH;
        const float* W2i = W2 + (size_t)i * HH * HH;

        rmsnorm_kernel<<<MM, 256, 0, stream>>>(s, ln_attn + i * HH, xn);
        gemm_kernel<<<gg, gbk, 0, stream>>>(xn, Qwi, Qb + i * HH, nullptr, nullptr, qb, 0);
        gemm_kernel<<<gg, gbk, 0, stream>>>(s,  Kwi, Kb + i * HH, apK,     nullptr, kb, 0);
        gemm_kernel<<<gg, gbk, 0, stream>>>(s,  Vwi, Vb + i * HH, apV,     nullptr, vb, 0);
        attn_kernel<<<MM, 256, 0, stream>>>(qb, kb, vb, tmK, tmV, tl, s);
        rmsnorm_kernel<<<MM, 256, 0, stream>>>(s, ln_ffn + i * HH, xn);
        gemm_kernel<<<gg, gbk, 0, stream>>>(xn, W1i, b1 + i * HH, nullptr, nullptr, tb, 1);
        gemm_kernel<<<gg, gbk, 0, stream>>>(tb, W2i, b2 + i * HH, s,       tl,      s,  0);
    }
    rmsnorm_kernel<<<MM, 256, 0, stream>>>(s, ln_last, out);
}

// Round 2
// 256.315 us; speedup vs baseline: 1.5318x; 1.5318x over previous
//
#include <hip/hip_runtime.h>
#include <math.h>

#define LLEN 256
#define HDIM 256
#define MM 1024
#define NEGV -4294967295.0f

// ---------------- fused GEMM core: C = [rmsnorm?](A) @ W^T + bias (+epilogue)
// BM=64, BN=32, BK=64, 256 threads, per-thread 4m x 2n register tile.
__device__ __forceinline__ void gemm_core(
    float* A_s, float* W_s, float* r_s,
    const float* __restrict__ A, const float* __restrict__ ln,
    const float* __restrict__ W, const float* __restrict__ bias,
    const float* __restrict__ addv, const float* __restrict__ resid,
    const unsigned char* __restrict__ tl, float* __restrict__ C,
    int relu, int m0, int n0)
{
    int t = threadIdx.x;
    int tm = t >> 4, tn = t & 15;
    float acc[4][2];
    #pragma unroll
    for (int i = 0; i < 4; ++i) { acc[i][0] = 0.f; acc[i][1] = 0.f; }
    float ssq[4] = {0.f, 0.f, 0.f, 0.f};

    for (int kc = 0; kc < HDIM; kc += 64) {
        #pragma unroll
        for (int i = 0; i < 4; ++i) {                 // stage A: 64 rows x 64 k
            int idx = t + 256 * i;
            int row = idx >> 4, c4 = idx & 15;
            float4 v = *(const float4*)&A[(size_t)(m0 + row) * HDIM + kc + c4 * 4];
            ssq[i] += v.x * v.x + v.y * v.y + v.z * v.z + v.w * v.w;
            if (ln) {
                v.x *= ln[kc + c4 * 4 + 0]; v.y *= ln[kc + c4 * 4 + 1];
                v.z *= ln[kc + c4 * 4 + 2]; v.w *= ln[kc + c4 * 4 + 3];
            }
            *(float4*)&A_s[row * 68 + c4 * 4] = v;
        }
        #pragma unroll
        for (int i = 0; i < 2; ++i) {                 // stage W: 32 rows x 64 k
            int idx = t + 256 * i;
            int row = idx >> 4, c4 = idx & 15;
            *(float4*)&W_s[row * 68 + c4 * 4] =
                *(const float4*)&W[(size_t)(n0 + row) * HDIM + kc + c4 * 4];
        }
        __syncthreads();
        #pragma unroll
        for (int k4 = 0; k4 < 16; ++k4) {
            float4 a0 = *(const float4*)&A_s[(tm * 4 + 0) * 68 + k4 * 4];
            float4 a1 = *(const float4*)&A_s[(tm * 4 + 1) * 68 + k4 * 4];
            float4 a2 = *(const float4*)&A_s[(tm * 4 + 2) * 68 + k4 * 4];
            float4 a3 = *(const float4*)&A_s[(tm * 4 + 3) * 68 + k4 * 4];
            float4 w0 = *(const float4*)&W_s[(tn * 2 + 0) * 68 + k4 * 4];
            float4 w1 = *(const float4*)&W_s[(tn * 2 + 1) * 68 + k4 * 4];
            acc[0][0] = fmaf(a0.x,w0.x,fmaf(a0.y,w0.y,fmaf(a0.z,w0.z,fmaf(a0.w,w0.w,acc[0][0]))));
            acc[0][1] = fmaf(a0.x,w1.x,fmaf(a0.y,w1.y,fmaf(a0.z,w1.z,fmaf(a0.w,w1.w,acc[0][1]))));
            acc[1][0] = fmaf(a1.x,w0.x,fmaf(a1.y,w0.y,fmaf(a1.z,w0.z,fmaf(a1.w,w0.w,acc[1][0]))));
            acc[1][1] = fmaf(a1.x,w1.x,fmaf(a1.y,w1.y,fmaf(a1.z,w1.z,fmaf(a1.w,w1.w,acc[1][1]))));
            acc[2][0] = fmaf(a2.x,w0.x,fmaf(a2.y,w0.y,fmaf(a2.z,w0.z,fmaf(a2.w,w0.w,acc[2][0]))));
            acc[2][1] = fmaf(a2.x,w1.x,fmaf(a2.y,w1.y,fmaf(a2.z,w1.z,fmaf(a2.w,w1.w,acc[2][1]))));
            acc[3][0] = fmaf(a3.x,w0.x,fmaf(a3.y,w0.y,fmaf(a3.z,w0.z,fmaf(a3.w,w0.w,acc[3][0]))));
            acc[3][1] = fmaf(a3.x,w1.x,fmaf(a3.y,w1.y,fmaf(a3.z,w1.z,fmaf(a3.w,w1.w,acc[3][1]))));
        }
        __syncthreads();
    }

    if (ln) {   // rmsnorm row factors: rows tm+16i, reduce over 16 lanes (tn)
        #pragma unroll
        for (int i = 0; i < 4; ++i) {
            float v = ssq[i];
            v += __shfl_xor(v, 1); v += __shfl_xor(v, 2);
            v += __shfl_xor(v, 4); v += __shfl_xor(v, 8);
            if (tn == 0) r_s[tm + 16 * i] = rsqrtf(v * (1.0f / HDIM) + 1e-8f);
        }
        __syncthreads();
    }

    #pragma unroll
    for (int mm = 0; mm < 4; ++mm) {
        int row = m0 + tm * 4 + mm;
        float rr = ln ? r_s[tm * 4 + mm] : 1.0f;
        float tlf = tl ? (tl[row] ? 0.f : 1.f) : 1.f;
        #pragma unroll
        for (int nn = 0; nn < 2; ++nn) {
            int col = n0 + tn * 2 + nn;
            float v = acc[mm][nn] * rr + bias[col];
            if (relu) v = fmaxf(v, 0.f);
            if (addv)  v += addv[(size_t)row * HDIM + col];
            if (resid) v += resid[(size_t)row * HDIM + col];
            v *= tlf;
            C[(size_t)row * HDIM + col] = v;
        }
    }
}

__global__ __launch_bounds__(256) void qkv_kernel(
    const float* __restrict__ s, const float* __restrict__ ln_attn,
    const float* __restrict__ Qw, const float* __restrict__ Qb,
    const float* __restrict__ Kw, const float* __restrict__ Kb,
    const float* __restrict__ Vw, const float* __restrict__ Vb,
    const float* __restrict__ apK, const float* __restrict__ apV,
    float* __restrict__ qb, float* __restrict__ kb, float* __restrict__ vb)
{
    __shared__ __align__(16) float A_s[64 * 68];
    __shared__ __align__(16) float W_s[32 * 68];
    __shared__ float r_s[64];
    int m0 = blockIdx.x * 64;
    int sel = blockIdx.y >> 3;
    int n0 = (blockIdx.y & 7) * 32;
    if (sel == 0)
        gemm_core(A_s, W_s, r_s, s, ln_attn, Qw, Qb, nullptr, nullptr, nullptr, qb, 0, m0, n0);
    else if (sel == 1)
        gemm_core(A_s, W_s, r_s, s, nullptr, Kw, Kb, apK, nullptr, nullptr, kb, 0, m0, n0);
    else
        gemm_core(A_s, W_s, r_s, s, nullptr, Vw, Vb, apV, nullptr, nullptr, vb, 0, m0, n0);
}

__global__ __launch_bounds__(256) void gemm_kernel(
    const float* __restrict__ A, const float* __restrict__ ln,
    const float* __restrict__ W, const float* __restrict__ bias,
    const float* __restrict__ resid, const unsigned char* __restrict__ tl,
    float* __restrict__ C, int relu)
{
    __shared__ __align__(16) float A_s[64 * 68];
    __shared__ __align__(16) float W_s[32 * 68];
    __shared__ float r_s[64];
    gemm_core(A_s, W_s, r_s, A, ln, W, bias, nullptr, resid, tl, C, relu,
              blockIdx.x * 64, blockIdx.y * 32);
}

// ---------------- Attention: one WG (512 thr) per (b,q), all 4 heads --------
__global__ __launch_bounds__(512) void attn_kernel(
    const float* __restrict__ Q, const float* __restrict__ Kp,
    const float* __restrict__ Vp, const float* __restrict__ tmK,
    const float* __restrict__ tmV, const unsigned char* __restrict__ tl,
    float* __restrict__ s)
{
    int bq = blockIdx.x;
    int b = bq >> 8, q = bq & 255;
    int tid = threadIdx.x;
    int w = tid >> 6, lane = tid & 63;

    __shared__ float w_s[4][257];
    __shared__ __align__(16) float out_s[8][256];

    float4 qf = ((const float4*)(Q + (size_t)bq * HDIM))[lane];  // head = lane>>4

    bool tlq = tl[bq] != 0;
    int kmax = tlq ? (LLEN - 1) : q;   // causal skip (masked cols -> A == 0 exactly)

    const float4* Kp4  = (const float4*)(Kp + (size_t)b * LLEN * HDIM);
    const float4* tmK4 = (const float4*)(tmK + (size_t)bq * LLEN * HDIM);

    for (int k = w; k <= kmax; k += 8) {
        float4 kv = Kp4[k * 64 + lane];
        float4 tv = tmK4[k * 64 + lane];
        float sc = qf.x * (kv.x + tv.x) + qf.y * (kv.y + tv.y)
                 + qf.z * (kv.z + tv.z) + qf.w * (kv.w + tv.w);
        sc += __shfl_xor(sc, 1);
        sc += __shfl_xor(sc, 2);
        sc += __shfl_xor(sc, 4);
        sc += __shfl_xor(sc, 8);
        if ((lane & 15) == 0) w_s[lane >> 4][k] = sc;
    }
    __syncthreads();

    if (w < 4) {   // softmax over k, head w; mask folded in (garbage never used)
        int h = w;
        float v0 = w_s[h][lane],       v1 = w_s[h][lane + 64];
        float v2 = w_s[h][lane + 128], v3 = w_s[h][lane + 192];
        v0 = (tlq || (lane       > q)) ? NEGV : v0 * 0.125f;
        v1 = (tlq || (lane + 64  > q)) ? NEGV : v1 * 0.125f;
        v2 = (tlq || (lane + 128 > q)) ? NEGV : v2 * 0.125f;
        v3 = (tlq || (lane + 192 > q)) ? NEGV : v3 * 0.125f;
        float mx = fmaxf(fmaxf(v0, v1), fmaxf(v2, v3));
        #pragma unroll
        for (int m2 = 1; m2 < 64; m2 <<= 1) mx = fmaxf(mx, __shfl_xor(mx, m2));
        float e0 = __expf(v0 - mx), e1 = __expf(v1 - mx);
        float e2 = __expf(v2 - mx), e3 = __expf(v3 - mx);
        float sm = e0 + e1 + e2 + e3;
        #pragma unroll
        for (int m2 = 1; m2 < 64; m2 <<= 1) sm += __shfl_xor(sm, m2);
        float inv = 1.0f / sm;
        w_s[h][lane] = e0 * inv;       w_s[h][lane + 64] = e1 * inv;
        w_s[h][lane + 128] = e2 * inv; w_s[h][lane + 192] = e3 * inv;
    }
    __syncthreads();

    const float4* Vp4  = (const float4*)(Vp + (size_t)b * LLEN * HDIM);
    const float4* tmV4 = (const float4*)(tmV + (size_t)bq * LLEN * HDIM);
    float4 acc = {0.f, 0.f, 0.f, 0.f};
    int hh = lane >> 4;
    for (int k = w; k <= kmax; k += 8) {
        float a = w_s[hh][k];
        float4 vv = Vp4[k * 64 + lane];
        float4 tv = tmV4[k * 64 + lane];
        acc.x = fmaf(a, vv.x + tv.x, acc.x);
        acc.y = fmaf(a, vv.y + tv.y, acc.y);
        acc.z = fmaf(a, vv.z + tv.z, acc.z);
        acc.w = fmaf(a, vv.w + tv.w, acc.w);
    }
    *(float4*)&out_s[w][lane * 4] = acc;
    __syncthreads();

    if (tid < 256) {
        float p = 0.f;
        #pragma unroll
        for (int j = 0; j < 8; ++j) p += out_s[j][tid];
        s[(size_t)bq * HDIM + tid] += p;
    }
}

// ---------------- final RMSNorm --------------------------------------------
__global__ __launch_bounds__(256) void rmsnorm_kernel(
    const float* __restrict__ x, const float* __restrict__ w, float* __restrict__ y)
{
    int row = blockIdx.x;
    int tid = threadIdx.x;
    float v = x[(size_t)row * HDIM + tid];
    float ss = v * v;
    #pragma unroll
    for (int m = 1; m < 64; m <<= 1) ss += __shfl_xor(ss, m);
    __shared__ float red[4];
    if ((tid & 63) == 0) red[tid >> 6] = ss;
    __syncthreads();
    float tot = red[0] + red[1] + red[2] + red[3];
    float r = rsqrtf(tot * (1.0f / HDIM) + 1e-8f);
    y[(size_t)row * HDIM + tid] = v * r * w[tid];
}

extern "C" void kernel_launch(void* const* d_in, const int* in_sizes, int n_in,
                              void* d_out, int out_size, void* d_ws, size_t ws_size,
                              hipStream_t stream)
{
    const float* seqs = (const float*)d_in[0];
    const unsigned char* tl = (const unsigned char*)d_in[2];
    const float* tmK = (const float*)d_in[3];
    const float* tmV = (const float*)d_in[4];
    const float* apK = (const float*)d_in[5];
    const float* apV = (const float*)d_in[6];
    const float* ln_attn = (const float*)d_in[7];
    const float* Qw = (const float*)d_in[8];
    const float* Qb = (const float*)d_in[9];
    const float* Kw = (const float*)d_in[10];
    const float* Kb = (const float*)d_in[11];
    const float* Vw = (const float*)d_in[12];
    const float* Vb = (const float*)d_in[13];
    const float* ln_ffn = (const float*)d_in[14];
    const float* W1 = (const float*)d_in[15];
    const float* b1 = (const float*)d_in[16];
    const float* W2 = (const float*)d_in[17];
    const float* b2 = (const float*)d_in[18];
    const float* ln_last = (const float*)d_in[19];
    float* out = (float*)d_out;

    const size_t NROW = (size_t)MM * HDIM;
    float* s  = (float*)d_ws;
    float* qb = s  + NROW;
    float* kb = qb + NROW;
    float* vb = kb + NROW;
    float* tb = vb + NROW;

    hipMemcpyAsync(s, seqs, NROW * sizeof(float), hipMemcpyDeviceToDevice, stream);

    for (int i = 0; i < 2; ++i) {
        const float* Qwi = Qw + (size_t)i * HDIM * HDIM;
        const float* Kwi = Kw + (size_t)i * HDIM * HDIM;
        const float* Vwi = Vw + (size_t)i * HDIM * HDIM;
        const float* W1i = W1 + (size_t)i * HDIM * HDIM;
        const float* W2i = W2 + (size_t)i * HDIM * HDIM;

        qkv_kernel<<<dim3(16, 24), 256, 0, stream>>>(
            s, ln_attn + i * HDIM, Qwi, Qb + i * HDIM, Kwi, Kb + i * HDIM,
            Vwi, Vb + i * HDIM, apK, apV, qb, kb, vb);
        attn_kernel<<<MM, 512, 0, stream>>>(qb, kb, vb, tmK, tmV, tl, s);
        gemm_kernel<<<dim3(16, 8), 256, 0, stream>>>(
            s, ln_ffn + i * HDIM, W1i, b1 + i * HDIM, nullptr, nullptr, tb, 1);
        gemm_kernel<<<dim3(16, 8), 256, 0, stream>>>(
            tb, nullptr, W2i, b2 + i * HDIM, s, tl, s, 0);
    }
    rmsnorm_kernel<<<MM, 256, 0, stream>>>(s, ln_last, out);
}

// Round 3
// 235.565 us; speedup vs baseline: 1.6667x; 1.0881x over previous
//
#include <hip/hip_runtime.h>
#include <math.h>

#define LLEN 256
#define HDIM 256
#define MM 1024
#define NEGV -4294967295.0f

// ---- fused GEMM core: C = [rmsnorm?](A) @ W^T + bias (+epilogue) ----------
// BM=64, BN=64, BK=64, 256 threads, per-thread 4m x 4n register tile.
__device__ __forceinline__ void gemm_core(
    float* A_s, float* W_s, float* r_s,
    const float* __restrict__ A, const float* __restrict__ ln,
    const float* __restrict__ W, const float* __restrict__ bias,
    const float* __restrict__ addv, const float* __restrict__ resid,
    const unsigned char* __restrict__ tl, float* __restrict__ C,
    int relu, int m0, int n0)
{
    int t = threadIdx.x;
    int tm = t >> 4, tn = t & 15;
    float acc[4][4];
    #pragma unroll
    for (int i = 0; i < 4; ++i)
        #pragma unroll
        for (int j = 0; j < 4; ++j) acc[i][j] = 0.f;
    float ssq[4] = {0.f, 0.f, 0.f, 0.f};

    for (int kc = 0; kc < HDIM; kc += 64) {
        #pragma unroll
        for (int i = 0; i < 4; ++i) {                 // stage A: 64 rows x 64 k
            int idx = t + 256 * i;
            int row = idx >> 4, c4 = idx & 15;
            float4 v = *(const float4*)&A[(size_t)(m0 + row) * HDIM + kc + c4 * 4];
            ssq[i] += v.x * v.x + v.y * v.y + v.z * v.z + v.w * v.w;
            if (ln) {
                v.x *= ln[kc + c4 * 4 + 0]; v.y *= ln[kc + c4 * 4 + 1];
                v.z *= ln[kc + c4 * 4 + 2]; v.w *= ln[kc + c4 * 4 + 3];
            }
            *(float4*)&A_s[row * 68 + c4 * 4] = v;
        }
        #pragma unroll
        for (int i = 0; i < 4; ++i) {                 // stage W: 64 rows x 64 k
            int idx = t + 256 * i;
            int row = idx >> 4, c4 = idx & 15;
            *(float4*)&W_s[row * 68 + c4 * 4] =
                *(const float4*)&W[(size_t)(n0 + row) * HDIM + kc + c4 * 4];
        }
        __syncthreads();
        #pragma unroll
        for (int k4 = 0; k4 < 16; ++k4) {
            float4 a[4], w[4];
            #pragma unroll
            for (int i = 0; i < 4; ++i)
                a[i] = *(const float4*)&A_s[(tm * 4 + i) * 68 + k4 * 4];
            #pragma unroll
            for (int j = 0; j < 4; ++j)
                w[j] = *(const float4*)&W_s[(tn * 4 + j) * 68 + k4 * 4];
            #pragma unroll
            for (int i = 0; i < 4; ++i)
                #pragma unroll
                for (int j = 0; j < 4; ++j)
                    acc[i][j] = fmaf(a[i].x, w[j].x, fmaf(a[i].y, w[j].y,
                                fmaf(a[i].z, w[j].z, fmaf(a[i].w, w[j].w, acc[i][j]))));
        }
        __syncthreads();
    }

    if (ln) {   // rmsnorm row factors: staging row tm+16i, reduce over 16 lanes
        #pragma unroll
        for (int i = 0; i < 4; ++i) {
            float v = ssq[i];
            v += __shfl_xor(v, 1); v += __shfl_xor(v, 2);
            v += __shfl_xor(v, 4); v += __shfl_xor(v, 8);
            if (tn == 0) r_s[tm + 16 * i] = rsqrtf(v * (1.0f / HDIM) + 1e-8f);
        }
        __syncthreads();
    }

    float4 bv = *(const float4*)&bias[n0 + tn * 4];
    #pragma unroll
    for (int mm = 0; mm < 4; ++mm) {
        int row = m0 + tm * 4 + mm;
        float rr = ln ? r_s[tm * 4 + mm] : 1.0f;
        float tlf = tl ? (tl[row] ? 0.f : 1.f) : 1.f;
        float4 v;
        v.x = acc[mm][0] * rr + bv.x; v.y = acc[mm][1] * rr + bv.y;
        v.z = acc[mm][2] * rr + bv.z; v.w = acc[mm][3] * rr + bv.w;
        if (relu) {
            v.x = fmaxf(v.x, 0.f); v.y = fmaxf(v.y, 0.f);
            v.z = fmaxf(v.z, 0.f); v.w = fmaxf(v.w, 0.f);
        }
        size_t base = (size_t)row * HDIM + n0 + tn * 4;
        if (addv) {
            float4 o = *(const float4*)&addv[base];
            v.x += o.x; v.y += o.y; v.z += o.z; v.w += o.w;
        }
        if (resid) {
            float4 o = *(const float4*)&resid[base];
            v.x += o.x; v.y += o.y; v.z += o.z; v.w += o.w;
        }
        v.x *= tlf; v.y *= tlf; v.z *= tlf; v.w *= tlf;
        *(float4*)&C[base] = v;
    }
}

__global__ __launch_bounds__(256) void qkv_kernel(
    const float* __restrict__ s, const float* __restrict__ ln_attn,
    const float* __restrict__ Qw, const float* __restrict__ Qb,
    const float* __restrict__ Kw, const float* __restrict__ Kb,
    const float* __restrict__ Vw, const float* __restrict__ Vb,
    const float* __restrict__ apK, const float* __restrict__ apV,
    float* __restrict__ qb, float* __restrict__ kb, float* __restrict__ vb)
{
    __shared__ __align__(16) float A_s[64 * 68];
    __shared__ __align__(16) float W_s[64 * 68];
    __shared__ float r_s[64];
    int m0 = blockIdx.x * 64;
    int sel = blockIdx.y >> 2;
    int n0 = (blockIdx.y & 3) * 64;
    if (sel == 0)
        gemm_core(A_s, W_s, r_s, s, ln_attn, Qw, Qb, nullptr, nullptr, nullptr, qb, 0, m0, n0);
    else if (sel == 1)
        gemm_core(A_s, W_s, r_s, s, nullptr, Kw, Kb, apK, nullptr, nullptr, kb, 0, m0, n0);
    else
        gemm_core(A_s, W_s, r_s, s, nullptr, Vw, Vb, apV, nullptr, nullptr, vb, 0, m0, n0);
}

__global__ __launch_bounds__(256) void gemm_kernel(
    const float* __restrict__ A, const float* __restrict__ ln,
    const float* __restrict__ W, const float* __restrict__ bias,
    const float* __restrict__ resid, const unsigned char* __restrict__ tl,
    float* __restrict__ C, int relu)
{
    __shared__ __align__(16) float A_s[64 * 68];
    __shared__ __align__(16) float W_s[64 * 68];
    __shared__ float r_s[64];
    gemm_core(A_s, W_s, r_s, A, ln, W, bias, nullptr, resid, tl, C, relu,
              blockIdx.x * 64, blockIdx.y * 64);
}

// ---- Attention: one WG (512 thr) per causal-complementary row PAIR --------
// WG g: b = g>>7, p = g&127 -> rows q=p and q=255-p. Work = 257 k-rows,
// uniform across all WGs (no CU-mapping assumption needed).
__global__ __launch_bounds__(512) void attn_kernel(
    const float* __restrict__ Q, const float* __restrict__ Kp,
    const float* __restrict__ Vp, const float* __restrict__ tmK,
    const float* __restrict__ tmV, const unsigned char* __restrict__ tl,
    float* __restrict__ s)
{
    int g = blockIdx.x;
    int b = g >> 7, p = g & 127;
    int tid = threadIdx.x;
    int w = tid >> 6, lane = tid & 63;
    int hh = lane >> 4;

    __shared__ float w_s[4][257];
    __shared__ __align__(16) float out_s[8][256];

    const float4* Kp4 = (const float4*)(Kp + (size_t)b * LLEN * HDIM);
    const float4* Vp4 = (const float4*)(Vp + (size_t)b * LLEN * HDIM);

    #pragma unroll
    for (int rr = 0; rr < 2; ++rr) {
        int q = rr ? (LLEN - 1 - p) : p;
        int bq = b * LLEN + q;
        float4 qf = ((const float4*)(Q + (size_t)bq * HDIM))[lane];  // head = lane>>4
        bool tlq = tl[bq] != 0;
        int kmax = tlq ? (LLEN - 1) : q;   // causal skip (masked cols -> A==0 exactly)

        const float4* tmK4 = (const float4*)(tmK + (size_t)bq * LLEN * HDIM);
        const float4* tmV4 = (const float4*)(tmV + (size_t)bq * LLEN * HDIM);

        for (int k = w; k <= kmax; k += 8) {
            float4 kv = Kp4[k * 64 + lane];
            float4 tv = tmK4[k * 64 + lane];
            float sc = qf.x * (kv.x + tv.x) + qf.y * (kv.y + tv.y)
                     + qf.z * (kv.z + tv.z) + qf.w * (kv.w + tv.w);
            sc += __shfl_xor(sc, 1);
            sc += __shfl_xor(sc, 2);
            sc += __shfl_xor(sc, 4);
            sc += __shfl_xor(sc, 8);
            if ((lane & 15) == 0) w_s[lane >> 4][k] = sc;
        }
        __syncthreads();

        if (w < 4) {   // softmax over k, head w; mask folded (stale vals never used)
            int h = w;
            float v0 = w_s[h][lane],       v1 = w_s[h][lane + 64];
            float v2 = w_s[h][lane + 128], v3 = w_s[h][lane + 192];
            v0 = (tlq || (lane       > q)) ? NEGV : v0 * 0.125f;
            v1 = (tlq || (lane + 64  > q)) ? NEGV : v1 * 0.125f;
            v2 = (tlq || (lane + 128 > q)) ? NEGV : v2 * 0.125f;
            v3 = (tlq || (lane + 192 > q)) ? NEGV : v3 * 0.125f;
            float mx = fmaxf(fmaxf(v0, v1), fmaxf(v2, v3));
            #pragma unroll
            for (int m2 = 1; m2 < 64; m2 <<= 1) mx = fmaxf(mx, __shfl_xor(mx, m2));
            float e0 = __expf(v0 - mx), e1 = __expf(v1 - mx);
            float e2 = __expf(v2 - mx), e3 = __expf(v3 - mx);
            float sm = e0 + e1 + e2 + e3;
            #pragma unroll
            for (int m2 = 1; m2 < 64; m2 <<= 1) sm += __shfl_xor(sm, m2);
            float inv = 1.0f / sm;
            w_s[h][lane] = e0 * inv;       w_s[h][lane + 64] = e1 * inv;
            w_s[h][lane + 128] = e2 * inv; w_s[h][lane + 192] = e3 * inv;
        }
        __syncthreads();

        float4 acc = {0.f, 0.f, 0.f, 0.f};
        for (int k = w; k <= kmax; k += 8) {
            float a = w_s[hh][k];
            float4 vv = Vp4[k * 64 + lane];
            float4 tv = tmV4[k * 64 + lane];
            acc.x = fmaf(a, vv.x + tv.x, acc.x);
            acc.y = fmaf(a, vv.y + tv.y, acc.y);
            acc.z = fmaf(a, vv.z + tv.z, acc.z);
            acc.w = fmaf(a, vv.w + tv.w, acc.w);
        }
        *(float4*)&out_s[w][lane * 4] = acc;
        __syncthreads();

        if (tid < 256) {
            float pp = 0.f;
            #pragma unroll
            for (int j = 0; j < 8; ++j) pp += out_s[j][tid];
            s[(size_t)bq * HDIM + tid] += pp;
        }
    }
}

// ---- final RMSNorm --------------------------------------------------------
__global__ __launch_bounds__(256) void rmsnorm_kernel(
    const float* __restrict__ x, const float* __restrict__ w, float* __restrict__ y)
{
    int row = blockIdx.x;
    int tid = threadIdx.x;
    float v = x[(size_t)row * HDIM + tid];
    float ss = v * v;
    #pragma unroll
    for (int m = 1; m < 64; m <<= 1) ss += __shfl_xor(ss, m);
    __shared__ float red[4];
    if ((tid & 63) == 0) red[tid >> 6] = ss;
    __syncthreads();
    float tot = red[0] + red[1] + red[2] + red[3];
    float r = rsqrtf(tot * (1.0f / HDIM) + 1e-8f);
    y[(size_t)row * HDIM + tid] = v * r * w[tid];
}

extern "C" void kernel_launch(void* const* d_in, const int* in_sizes, int n_in,
                              void* d_out, int out_size, void* d_ws, size_t ws_size,
                              hipStream_t stream)
{
    const float* seqs = (const float*)d_in[0];
    const unsigned char* tl = (const unsigned char*)d_in[2];
    const float* tmK = (const float*)d_in[3];
    const float* tmV = (const float*)d_in[4];
    const float* apK = (const float*)d_in[5];
    const float* apV = (const float*)d_in[6];
    const float* ln_attn = (const float*)d_in[7];
    const float* Qw = (const float*)d_in[8];
    const float* Qb = (const float*)d_in[9];
    const float* Kw = (const float*)d_in[10];
    const float* Kb = (const float*)d_in[11];
    const float* Vw = (const float*)d_in[12];
    const float* Vb = (const float*)d_in[13];
    const float* ln_ffn = (const float*)d_in[14];
    const float* W1 = (const float*)d_in[15];
    const float* b1 = (const float*)d_in[16];
    const float* W2 = (const float*)d_in[17];
    const float* b2 = (const float*)d_in[18];
    const float* ln_last = (const float*)d_in[19];
    float* out = (float*)d_out;

    const size_t NROW = (size_t)MM * HDIM;
    float* s  = (float*)d_ws;
    float* qb = s  + NROW;
    float* kb = qb + NROW;
    float* vb = kb + NROW;
    float* tb = vb + NROW;

    hipMemcpyAsync(s, seqs, NROW * sizeof(float), hipMemcpyDeviceToDevice, stream);

    for (int i = 0; i < 2; ++i) {
        const float* Qwi = Qw + (size_t)i * HDIM * HDIM;
        const float* Kwi = Kw + (size_t)i * HDIM * HDIM;
        const float* Vwi = Vw + (size_t)i * HDIM * HDIM;
        const float* W1i = W1 + (size_t)i * HDIM * HDIM;
        const float* W2i = W2 + (size_t)i * HDIM * HDIM;

        qkv_kernel<<<dim3(16, 12), 256, 0, stream>>>(
            s, ln_attn + i * HDIM, Qwi, Qb + i * HDIM, Kwi, Kb + i * HDIM,
            Vwi, Vb + i * HDIM, apK, apV, qb, kb, vb);
        attn_kernel<<<512, 512, 0, stream>>>(qb, kb, vb, tmK, tmV, tl, s);
        gemm_kernel<<<dim3(16, 4), 256, 0, stream>>>(
            s, ln_ffn + i * HDIM, W1i, b1 + i * HDIM, nullptr, nullptr, tb, 1);
        gemm_kernel<<<dim3(16, 4), 256, 0, stream>>>(
            tb, nullptr, W2i, b2 + i * HDIM, s, tl, s, 0);
    }
    rmsnorm_kernel<<<MM, 256, 0, stream>>>(s, ln_last, out);
}